// Round 1
// baseline (229.656 us; speedup 1.0000x reference)
//
#include <hip/hip_runtime.h>
#include <hip/hip_bf16.h>
#include <stdint.h>

#define M_DIM 4096
#define N_DIM 4096
#define K_DIM 4096
#define NH 128
#define NW 128

typedef short bf16x8 __attribute__((ext_vector_type(8)));
typedef short bf16x4 __attribute__((ext_vector_type(4)));
typedef float f32x4 __attribute__((ext_vector_type(4)));

__device__ __forceinline__ short f2bf(float f) {
  union { float f; unsigned u; } c; c.f = f;
  unsigned u = c.u;
  unsigned r = (u + 0x7fffu + ((u >> 16) & 1u)) >> 16;  // RNE
  return (short)r;
}

// ---------------- kernel 1: per-32x32-block mask ----------------
__global__ __launch_bounds__(256) void k_block_mask(const int* __restrict__ mask,
                                                    const float* __restrict__ conv_bias,
                                                    int* __restrict__ bm) {
  const int bw = blockIdx.x, bh = blockIdx.y;
  const int t = threadIdx.x;
  const int row = t >> 3;          // 32 rows, 8 threads/row
  const int c4 = (t & 7) << 2;     // 4 ints each
  const int4* p = (const int4*)(mask + (size_t)(bh * 32 + row) * K_DIM + bw * 32 + c4);
  int4 v = *p;
  int s = v.x + v.y + v.z + v.w;
#pragma unroll
  for (int off = 32; off > 0; off >>= 1) s += __shfl_down(s, off);
  __shared__ int red[4];
  if ((t & 63) == 0) red[t >> 6] = s;
  __syncthreads();
  if (t == 0) {
    float tot = (float)(red[0] + red[1] + red[2] + red[3]) + conv_bias[0];
    bm[bh * NW + bw] = (tot > 0.0f) ? 1 : 0;
  }
}

// ---------------- kernel 2: data f32 -> bf16 ----------------
__global__ __launch_bounds__(256) void k_cvt_data(const float* __restrict__ in,
                                                  short* __restrict__ ob) {
  size_t i = (size_t)blockIdx.x * 256 + threadIdx.x;  // float4 index
  f32x4 v = ((const f32x4*)in)[i];
  bf16x4 o;
  o[0] = f2bf(v[0]); o[1] = f2bf(v[1]); o[2] = f2bf(v[2]); o[3] = f2bf(v[3]);
  ((bf16x4*)ob)[i] = o;
}

// ---------------- kernel 3: weight f32 -> masked bf16 ----------------
__global__ __launch_bounds__(256) void k_cvt_weight(const float* __restrict__ w,
                                                    const int* __restrict__ bm,
                                                    short* __restrict__ ob) {
  size_t i = (size_t)blockIdx.x * 256 + threadIdx.x;  // float4 index
  int n = (int)(i >> 10);           // 1024 float4 per row
  int k = ((int)i & 1023) << 2;
  float m = bm[((n >> 5) << 7) + (k >> 5)] ? 1.0f : 0.0f;
  f32x4 v = ((const f32x4*)w)[i];
  bf16x4 o;
  o[0] = f2bf(v[0] * m); o[1] = f2bf(v[1] * m);
  o[2] = f2bf(v[2] * m); o[3] = f2bf(v[3] * m);
  ((bf16x4*)ob)[i] = o;
}

// ---------------- kernel 4: bf16 NT GEMM (m97 structure) ----------------
// C[M,N] = A[M,K] * B[N,K]^T + bias ; 128x128 tile, BK=32, 4 waves (2x2),
// each wave 64x64 via 4x4 x mfma_f32_16x16x32_bf16, global_load_lds width 16.
__global__ __launch_bounds__(256) void k_gemm(const short* __restrict__ Ab,
                                              const short* __restrict__ Bb,
                                              const float* __restrict__ bias,
                                              float* __restrict__ out) {
  __shared__ short As[128 * 32];
  __shared__ short Bs[128 * 32];
  const int tid = threadIdx.x;
  const int wv = tid >> 6, lane = tid & 63;
  const int wr = wv >> 1, wc = wv & 1;
  const int r = lane & 15, g = lane >> 4;
  const int aRow0 = blockIdx.y * 128;
  const int bCol0 = blockIdx.x * 128;

  f32x4 acc[4][4];
#pragma unroll
  for (int m = 0; m < 4; ++m)
#pragma unroll
    for (int n = 0; n < 4; ++n) acc[m][n] = (f32x4){0.f, 0.f, 0.f, 0.f};

  for (int kt = 0; kt < K_DIM / 32; ++kt) {
    const int k0 = kt * 32;
    // stage A and B tiles: 8192 B each = 256 thr x 2 calls x 16 B
#pragma unroll
    for (int i = 0; i < 2; ++i) {
      int li = i * 256 + tid;
      int row = li >> 2, seg = li & 3;
      const short* ga = Ab + (size_t)(aRow0 + row) * K_DIM + k0 + seg * 8;
      const short* gb = Bb + (size_t)(bCol0 + row) * K_DIM + k0 + seg * 8;
      short* la = As + (size_t)(i * 256 + wv * 64) * 8;  // wave-uniform base
      short* lb = Bs + (size_t)(i * 256 + wv * 64) * 8;
      __builtin_amdgcn_global_load_lds((__attribute__((address_space(1))) void*)ga,
                                       (__attribute__((address_space(3))) void*)la,
                                       16, 0, 0);
      __builtin_amdgcn_global_load_lds((__attribute__((address_space(1))) void*)gb,
                                       (__attribute__((address_space(3))) void*)lb,
                                       16, 0, 0);
    }
    __syncthreads();  // compiler drains vmcnt(0) before barrier -> LDS valid

    bf16x8 a[4], b[4];
#pragma unroll
    for (int m = 0; m < 4; ++m)
      a[m] = *(const bf16x8*)&As[(wr * 64 + m * 16 + r) * 32 + g * 8];
#pragma unroll
    for (int n = 0; n < 4; ++n)
      b[n] = *(const bf16x8*)&Bs[(wc * 64 + n * 16 + r) * 32 + g * 8];
#pragma unroll
    for (int m = 0; m < 4; ++m)
#pragma unroll
      for (int n = 0; n < 4; ++n)
        acc[m][n] = __builtin_amdgcn_mfma_f32_16x16x32_bf16(a[m], b[n], acc[m][n], 0, 0, 0);
    __syncthreads();  // protect LDS before next stage
  }

  // epilogue: C/D layout col=lane&15, row=(lane>>4)*4+j  [m89/m91 verified]
  const int cRow0 = aRow0 + wr * 64 + g * 4;
  const int cCol0 = bCol0 + wc * 64 + r;
#pragma unroll
  for (int n = 0; n < 4; ++n) {
    int col = cCol0 + n * 16;
    float bz = bias[col];
#pragma unroll
    for (int m = 0; m < 4; ++m) {
      int row0 = cRow0 + m * 16;
#pragma unroll
      for (int j = 0; j < 4; ++j)
        out[(size_t)(row0 + j) * N_DIM + col] = acc[m][n][j] + bz;
    }
  }
}

// ---------------- fallback (ws too small): naive fp32 ----------------
__global__ __launch_bounds__(256) void k_naive(const float* __restrict__ A,
                                               const float* __restrict__ W,
                                               const float* __restrict__ bias,
                                               const int* __restrict__ bm,
                                               float* __restrict__ out) {
  int col = blockIdx.x * 16 + (threadIdx.x & 15);
  int row = blockIdx.y * 16 + (threadIdx.x >> 4);
  float s = 0.f;
  for (int kb = 0; kb < K_DIM / 32; ++kb) {
    if (bm[(col >> 5) * NW + kb]) {
      int kbase = kb * 32;
#pragma unroll 8
      for (int k = 0; k < 32; ++k)
        s += A[(size_t)row * K_DIM + kbase + k] * W[(size_t)col * K_DIM + kbase + k];
    }
  }
  out[(size_t)row * N_DIM + col] = s + bias[col];
}

extern "C" void kernel_launch(void* const* d_in, const int* in_sizes, int n_in,
                              void* d_out, int out_size, void* d_ws, size_t ws_size,
                              hipStream_t stream) {
  const float* data = (const float*)d_in[0];
  const float* weight = (const float*)d_in[1];
  const float* bias = (const float*)d_in[2];
  const int* mask = (const int*)d_in[3];
  const float* conv_bias = (const float*)d_in[4];
  float* out = (float*)d_out;

  int* bm = (int*)d_ws;
  const size_t off_a = 65536;
  const size_t off_b = off_a + (size_t)M_DIM * K_DIM * 2;
  const size_t needed = off_b + (size_t)N_DIM * K_DIM * 2;

  k_block_mask<<<dim3(NW, NH), 256, 0, stream>>>(mask, conv_bias, bm);

  if (ws_size >= needed) {
    short* Abf = (short*)((char*)d_ws + off_a);
    short* Wbf = (short*)((char*)d_ws + off_b);
    k_cvt_data<<<dim3((M_DIM * (K_DIM / 4)) / 256), 256, 0, stream>>>(data, Abf);
    k_cvt_weight<<<dim3((N_DIM * (K_DIM / 4)) / 256), 256, 0, stream>>>(weight, bm, Wbf);
    k_gemm<<<dim3(N_DIM / 128, M_DIM / 128), 256, 0, stream>>>(Abf, Wbf, bias, out);
  } else {
    k_naive<<<dim3(N_DIM / 16, M_DIM / 16), 256, 0, stream>>>(data, weight, bias, bm, out);
  }
}

// Round 3
// 175.595 us; speedup vs baseline: 1.3079x; 1.3079x over previous
//
#include <hip/hip_runtime.h>
#include <hip/hip_bf16.h>
#include <stdint.h>

#define M_DIM 4096
#define N_DIM 4096
#define K_DIM 4096
#define NH 128
#define NW 128
#define NKT 64   // K-tiles of BK=64

typedef short bf16x8 __attribute__((ext_vector_type(8)));
typedef short bf16x4 __attribute__((ext_vector_type(4)));
typedef float f32x4 __attribute__((ext_vector_type(4)));

#define MFMA(a, b, c) __builtin_amdgcn_mfma_f32_16x16x32_bf16((a), (b), (c), 0, 0, 0)

__device__ __forceinline__ short f2bf(float f) {
  union { float f; unsigned u; } c; c.f = f;
  unsigned u = c.u;
  unsigned r = (u + 0x7fffu + ((u >> 16) & 1u)) >> 16;  // RNE
  return (short)r;
}

// ---------------- kernel 1: per-32x32-block mask ----------------
__global__ __launch_bounds__(256) void k_block_mask(const int* __restrict__ mask,
                                                    const float* __restrict__ conv_bias,
                                                    int* __restrict__ bm) {
  const int bw = blockIdx.x, bh = blockIdx.y;
  const int t = threadIdx.x;
  const int row = t >> 3;
  const int c4 = (t & 7) << 2;
  const int4* p = (const int4*)(mask + (size_t)(bh * 32 + row) * K_DIM + bw * 32 + c4);
  int4 v = *p;
  int s = v.x + v.y + v.z + v.w;
#pragma unroll
  for (int off = 32; off > 0; off >>= 1) s += __shfl_down(s, off);
  __shared__ int red[4];
  if ((t & 63) == 0) red[t >> 6] = s;
  __syncthreads();
  if (t == 0) {
    float tot = (float)(red[0] + red[1] + red[2] + red[3]) + conv_bias[0];
    bm[bh * NW + bw] = (tot > 0.0f) ? 1 : 0;
  }
}

// ---------------- kernel 2: data f32 -> bf16 ----------------
__global__ __launch_bounds__(256) void k_cvt_data(const float* __restrict__ in,
                                                  short* __restrict__ ob) {
  size_t i = (size_t)blockIdx.x * 256 + threadIdx.x;
  f32x4 v = ((const f32x4*)in)[i];
  bf16x4 o;
  o[0] = f2bf(v[0]); o[1] = f2bf(v[1]); o[2] = f2bf(v[2]); o[3] = f2bf(v[3]);
  ((bf16x4*)ob)[i] = o;
}

// ---------------- kernel 3: weight f32 -> masked bf16 ----------------
__global__ __launch_bounds__(256) void k_cvt_weight(const float* __restrict__ w,
                                                    const int* __restrict__ bm,
                                                    short* __restrict__ ob) {
  size_t i = (size_t)blockIdx.x * 256 + threadIdx.x;
  int n = (int)(i >> 10);
  int k = ((int)i & 1023) << 2;
  float m = bm[((n >> 5) << 7) + (k >> 5)] ? 1.0f : 0.0f;
  f32x4 v = ((const f32x4*)w)[i];
  bf16x4 o;
  o[0] = f2bf(v[0] * m); o[1] = f2bf(v[1] * m);
  o[2] = f2bf(v[2] * m); o[3] = f2bf(v[3] * m);
  ((bf16x4*)ob)[i] = o;
}

// ---------------- kernel 4: 256x256 8-phase bf16 NT GEMM ----------------
// 8 waves (2Mx4N), BK=64 split into 2 ks-slabs [256][32] (64B rows), double-buffered.
// Swizzle: physical colseg = logical colseg ^ (row bits 2:1); applied on the
// pre-swizzled global_load_lds SOURCE and on the ds_read address (both sides).
// Counted vmcnt(4) once per K-tile before the K-tile-end barrier; raw s_barrier
// everywhere (no __syncthreads -> no vmcnt(0) drain in the main loop).
__global__ __launch_bounds__(512, 2) void k_gemm256(const short* __restrict__ Ab,
                                                    const short* __restrict__ Bb,
                                                    const float* __restrict__ bias,
                                                    float* __restrict__ out) {
  __shared__ short Asm[2][2][256][32];  // [buf][ks][row][col] 64 KB
  __shared__ short Bsm[2][2][256][32];  // 64 KB

  const int tid = threadIdx.x;
  const int wid = tid >> 6, lane = tid & 63;
  const int wr = wid >> 2, wc = wid & 3;
  const int r = lane & 15, g0 = lane >> 4;
  const int gs = g0 ^ ((r >> 1) & 3);      // swizzled col-seg for ds_read

  // XCD-aware swizzle: 256 wgs, 8 XCDs, 32/XCD (bijective since 256%8==0)
  const int swz = (blockIdx.x & 7) * 32 + (blockIdx.x >> 3);
  const int bx = swz & 15, by = swz >> 4;
  const int rowM = by * 256, colN = bx * 256;

  // staging geometry: 512 thr x 16B = one (half,ks) 8KB region, linear LDS
  const int srow = tid >> 2;                         // 0..127 within half
  const int sseg = (tid & 3) ^ ((tid >> 3) & 3);     // pre-swizzled source seg
  const int swave = (tid >> 6) * 512;                // wave-uniform LDS base (shorts)

#define STAGE(G, row0, kt, h, ks, L)                                                   \
  __builtin_amdgcn_global_load_lds(                                                    \
      (const __attribute__((address_space(1))) void*)((G) +                            \
          (size_t)((row0) + (h) * 128 + srow) * K_DIM + (kt) * 64 + (ks) * 32 + sseg * 8), \
      (__attribute__((address_space(3))) void*)(&L[ks][(h) * 128][0] + swave), 16, 0, 0)

#define LDA(buf, ks, m) (*(const bf16x8*)&Asm[buf][ks][wr * 128 + (m) * 16 + r][gs * 8])
#define LDB(buf, ks, n) (*(const bf16x8*)&Bsm[buf][ks][wc * 64 + (n) * 16 + r][gs * 8])

  f32x4 acc[8][4];
#pragma unroll
  for (int m = 0; m < 8; ++m)
#pragma unroll
    for (int n = 0; n < 4; ++n) acc[m][n] = (f32x4){0.f, 0.f, 0.f, 0.f};

  // prologue: kt0 fully (8 loads), kt1 A-halves (4 loads)
  STAGE(Ab, rowM, 0, 0, 0, Asm[0]); STAGE(Ab, rowM, 0, 0, 1, Asm[0]);
  STAGE(Ab, rowM, 0, 1, 0, Asm[0]); STAGE(Ab, rowM, 0, 1, 1, Asm[0]);
  STAGE(Bb, colN, 0, 0, 0, Bsm[0]); STAGE(Bb, colN, 0, 0, 1, Bsm[0]);
  STAGE(Bb, colN, 0, 1, 0, Bsm[0]); STAGE(Bb, colN, 0, 1, 1, Bsm[0]);
  STAGE(Ab, rowM, 1, 0, 0, Asm[1]); STAGE(Ab, rowM, 1, 0, 1, Asm[1]);
  STAGE(Ab, rowM, 1, 1, 0, Asm[1]); STAGE(Ab, rowM, 1, 1, 1, Asm[1]);
  asm volatile("s_waitcnt vmcnt(4)" ::: "memory");
  __builtin_amdgcn_s_barrier();

  for (int u = 0; u < NKT; ++u) {
    const int bsel = u & 1, nsel = bsel ^ 1;
    bf16x8 a[8], p, q;

    // ---- P0: ks0, n={0,1}; stage (u+1).Bhalf0 ----
#pragma unroll
    for (int m = 0; m < 8; ++m) a[m] = LDA(bsel, 0, m);
    p = LDB(bsel, 0, 0); q = LDB(bsel, 0, 1);
    if (u + 1 < NKT) { STAGE(Bb, colN, u + 1, 0, 0, Bsm[nsel]); STAGE(Bb, colN, u + 1, 0, 1, Bsm[nsel]); }
    __builtin_amdgcn_s_barrier();
    __builtin_amdgcn_s_setprio(1);
#pragma unroll
    for (int m = 0; m < 8; ++m) acc[m][0] = MFMA(a[m], p, acc[m][0]);
#pragma unroll
    for (int m = 0; m < 8; ++m) acc[m][1] = MFMA(a[m], q, acc[m][1]);
    __builtin_amdgcn_s_setprio(0);
    __builtin_amdgcn_s_barrier();

    // ---- P1: ks0, n={2,3}; stage (u+1).Bhalf1 ----
    p = LDB(bsel, 0, 2); q = LDB(bsel, 0, 3);
    if (u + 1 < NKT) { STAGE(Bb, colN, u + 1, 1, 0, Bsm[nsel]); STAGE(Bb, colN, u + 1, 1, 1, Bsm[nsel]); }
    __builtin_amdgcn_s_barrier();
    __builtin_amdgcn_s_setprio(1);
#pragma unroll
    for (int m = 0; m < 8; ++m) acc[m][2] = MFMA(a[m], p, acc[m][2]);
#pragma unroll
    for (int m = 0; m < 8; ++m) acc[m][3] = MFMA(a[m], q, acc[m][3]);
    __builtin_amdgcn_s_setprio(0);
    __builtin_amdgcn_s_barrier();

    // ---- P2: ks1, n={0,1}; no stage ----
#pragma unroll
    for (int m = 0; m < 8; ++m) a[m] = LDA(bsel, 1, m);
    p = LDB(bsel, 1, 0); q = LDB(bsel, 1, 1);
    __builtin_amdgcn_s_barrier();
    __builtin_amdgcn_s_setprio(1);
#pragma unroll
    for (int m = 0; m < 8; ++m) acc[m][0] = MFMA(a[m], p, acc[m][0]);
#pragma unroll
    for (int m = 0; m < 8; ++m) acc[m][1] = MFMA(a[m], q, acc[m][1]);
    __builtin_amdgcn_s_setprio(0);
    __builtin_amdgcn_s_barrier();

    // ---- P3: ks1, n={2,3}; stage (u+2).A both halves; vmcnt; K-tile barrier ----
    p = LDB(bsel, 1, 2); q = LDB(bsel, 1, 3);
    if (u + 2 < NKT) {
      STAGE(Ab, rowM, u + 2, 0, 0, Asm[bsel]); STAGE(Ab, rowM, u + 2, 0, 1, Asm[bsel]);
      STAGE(Ab, rowM, u + 2, 1, 0, Asm[bsel]); STAGE(Ab, rowM, u + 2, 1, 1, Asm[bsel]);
    }
    __builtin_amdgcn_s_barrier();
    __builtin_amdgcn_s_setprio(1);
#pragma unroll
    for (int m = 0; m < 8; ++m) acc[m][2] = MFMA(a[m], p, acc[m][2]);
#pragma unroll
    for (int m = 0; m < 8; ++m) acc[m][3] = MFMA(a[m], q, acc[m][3]);
    __builtin_amdgcn_s_setprio(0);
    if (u + 2 < NKT) {
      asm volatile("s_waitcnt vmcnt(4)" ::: "memory");  // (u+1) fully landed; (u+2).A may fly
    } else {
      asm volatile("s_waitcnt vmcnt(0)" ::: "memory");  // tail: no A-stage issued, drain B
    }
    __builtin_amdgcn_s_barrier();
  }

  // epilogue: C/D layout col=lane&15 (=r), row=(lane>>4)*4+j (=g0*4+j)
  const int orow = rowM + wr * 128;
  const int ocol = colN + wc * 64;
#pragma unroll
  for (int n = 0; n < 4; ++n) {
    int col = ocol + n * 16 + r;
    float bz = bias[col];
#pragma unroll
    for (int m = 0; m < 8; ++m) {
      int row0 = orow + m * 16 + g0 * 4;
#pragma unroll
      for (int j = 0; j < 4; ++j)
        out[(size_t)(row0 + j) * N_DIM + col] = acc[m][n][j] + bz;
    }
  }
#undef STAGE
#undef LDA
#undef LDB
}

// ---------------- fallback (ws too small): naive fp32 ----------------
__global__ __launch_bounds__(256) void k_naive(const float* __restrict__ A,
                                               const float* __restrict__ W,
                                               const float* __restrict__ bias,
                                               const int* __restrict__ bm,
                                               float* __restrict__ out) {
  int col = blockIdx.x * 16 + (threadIdx.x & 15);
  int row = blockIdx.y * 16 + (threadIdx.x >> 4);
  float s = 0.f;
  for (int kb = 0; kb < K_DIM / 32; ++kb) {
    if (bm[(col >> 5) * NW + kb]) {
      int kbase = kb * 32;
#pragma unroll 8
      for (int k = 0; k < 32; ++k)
        s += A[(size_t)row * K_DIM + kbase + k] * W[(size_t)col * K_DIM + kbase + k];
    }
  }
  out[(size_t)row * N_DIM + col] = s + bias[col];
}

extern "C" void kernel_launch(void* const* d_in, const int* in_sizes, int n_in,
                              void* d_out, int out_size, void* d_ws, size_t ws_size,
                              hipStream_t stream) {
  const float* data = (const float*)d_in[0];
  const float* weight = (const float*)d_in[1];
  const float* bias = (const float*)d_in[2];
  const int* mask = (const int*)d_in[3];
  const float* conv_bias = (const float*)d_in[4];
  float* out = (float*)d_out;

  int* bm = (int*)d_ws;
  const size_t off_a = 65536;
  const size_t off_b = off_a + (size_t)M_DIM * K_DIM * 2;
  const size_t needed = off_b + (size_t)N_DIM * K_DIM * 2;

  k_block_mask<<<dim3(NW, NH), 256, 0, stream>>>(mask, conv_bias, bm);

  if (ws_size >= needed) {
    short* Abf = (short*)((char*)d_ws + off_a);
    short* Wbf = (short*)((char*)d_ws + off_b);
    k_cvt_data<<<dim3((M_DIM * (K_DIM / 4)) / 256), 256, 0, stream>>>(data, Abf);
    k_cvt_weight<<<dim3((N_DIM * (K_DIM / 4)) / 256), 256, 0, stream>>>(weight, bm, Wbf);
    k_gemm256<<<dim3(256), 512, 0, stream>>>(Abf, Wbf, bias, out);
  } else {
    k_naive<<<dim3(N_DIM / 16, M_DIM / 16), 256, 0, stream>>>(data, weight, bias, bm, out);
  }
}